// Round 12
// baseline (1482.582 us; speedup 1.0000x reference)
//
#include <hip/hip_runtime.h>
#include <hip/hip_bf16.h>

// Problem constants
#define Bz 16
#define Tz 32
#define Sz 128
#define TPz 4
#define Mz (Bz*Sz)          // 2048 rows
#define NSTEP (Tz-1)        // 31

typedef __bf16 bf16x8 __attribute__((ext_vector_type(8)));
typedef float  f32x4  __attribute__((ext_vector_type(4)));

#define MFMA __builtin_amdgcn_mfma_f32_16x16x32_bf16
#define SCHED_FENCE() __builtin_amdgcn_sched_barrier(0)

__device__ __forceinline__ float sigf(float x) { return 1.f/(1.f + __expf(-x)); }

// halo row load: rel row v>>5 (s = s0-2+row), seg v&31; zero outside [0,128)
__device__ __forceinline__ bf16x8 ld_halo(const __bf16* base512, int s0, int v) {
    const int row = v >> 5, seg = v & 31, s = s0 - 2 + row;
    bf16x8 val;
    if ((unsigned)s < 128u)
        val = *(const bf16x8*)&base512[(size_t)s*512 + seg*8];
    else {
        #pragma unroll
        for (int i = 0; i < 8; ++i) val[i] = (__bf16)0.f;
    }
    return val;
}

// ---------------------------------------------------------------------------
// prep3 (verified): pack weights (fp32) into bf16 MFMA B-fragment order
// ---------------------------------------------------------------------------
__global__ __launch_bounds__(256) void prep3(
    const float* __restrict__ encWq, const float* __restrict__ encWk,
    const float* __restrict__ encWv, const float* __restrict__ encWg,
    const float* __restrict__ decWq, const float* __restrict__ decWk,
    const float* __restrict__ decWv, const float* __restrict__ decWg,
    const float* __restrict__ embW,
    __bf16* __restrict__ Pqkv_e, __bf16* __restrict__ Pqkv_d,
    __bf16* __restrict__ Pemb,   __bf16* __restrict__ Pg_e,
    __bf16* __restrict__ Pg_d)
{
    int id = blockIdx.x * 256 + threadIdx.x;
    if (id < 768*256) {
        int f = id >> 9, e = id & 511, l = e >> 3, j = e & 7;
        int nt = f >> 3, kt = f & 7;
        int n = nt*16 + (l & 15), k = kt*32 + (l >> 4)*8 + j;
        float v = (n < 256) ? encWq[k*256 + n]
                : (n < 512) ? encWk[k*256 + (n-256)]
                            : encWv[k*256 + (n-512)];
        Pqkv_e[id] = (__bf16)v; return;
    }
    id -= 768*256;
    if (id < 768*256) {
        int f = id >> 9, e = id & 511, l = e >> 3, j = e & 7;
        int nt = f >> 3, kt = f & 7;
        int n = nt*16 + (l & 15), k = kt*32 + (l >> 4)*8 + j;
        float v = (n < 256) ? decWq[k*256 + n]
                : (n < 512) ? decWk[k*256 + (n-256)]
                            : decWv[k*256 + (n-512)];
        Pqkv_d[id] = (__bf16)v; return;
    }
    id -= 768*256;
    if (id < 256*256) {
        int f = id >> 9, e = id & 511, l = e >> 3, j = e & 7;
        int nt = f >> 3, kt = f & 7;
        int n = nt*16 + (l & 15), k = kt*32 + (l >> 4)*8 + j;
        Pemb[id] = (__bf16)embW[k*256 + n]; return;
    }
    id -= 256*256;
    if (id < 1024*512) {
        int f = id >> 9, e = id & 511, l = e >> 3, j = e & 7;
        int nt = f >> 4, kt = f & 15;
        int cht = nt >> 2, g = nt & 3;
        int ch = cht*16 + (l & 15), k = kt*32 + (l >> 4)*8 + j;
        Pg_e[id] = (__bf16)encWg[(size_t)(3 + k)*1024 + g*256 + ch]; return;
    }
    id -= 1024*512;
    if (id < 1024*768) {
        int f = id >> 9, e = id & 511, l = e >> 3, j = e & 7;
        int nt = f / 24, kt = f % 24;
        int cht = nt >> 2, g = nt & 3;
        int ch = cht*16 + (l & 15), k = kt*32 + (l >> 4)*8 + j;
        Pg_d[id] = (__bf16)decWg[(size_t)k*1024 + g*256 + ch]; return;
    }
}

// ---------------------------------------------------------------------------
// qkv GEMM from 36-row staged state (stride 264) -> qL (own 32 rows), kvL (36).
// R12: chunks widened 2-kt -> 4-kt (half the exposed-latency windows); fence
// between each chunk's 20-load group and its MFMAs. MFMA order unchanged.
// ---------------------------------------------------------------------------
__device__ __forceinline__ void qkv_lds(
    const __bf16* src264, const __bf16* __restrict__ P,
    __bf16* qL, __bf16* kvL, int tid)
{
    const int w = tid >> 6, lane = tid & 63, quad = (lane >> 4), lr = lane & 15;
    #pragma unroll
    for (int ng = 0; ng < 3; ++ng) {
        const int ntA = w*6 + ng*2;
        f32x4 acc[2][3];
        #pragma unroll
        for (int i = 0; i < 2; ++i)
            #pragma unroll
            for (int m = 0; m < 3; ++m) acc[i][m] = f32x4{0.f,0.f,0.f,0.f};
        #pragma unroll
        for (int kc = 0; kc < 8; kc += 4) {
            bf16x8 a[4][3], b[4][2];
            #pragma unroll
            for (int u = 0; u < 4; ++u) {
                const int kt = kc + u;
                a[u][0] = *(const bf16x8*)&src264[(lr)*264      + kt*32 + quad*8];
                a[u][1] = *(const bf16x8*)&src264[(16 + lr)*264 + kt*32 + quad*8];
                a[u][2] = *(const bf16x8*)&src264[(32 + lr)*264 + kt*32 + quad*8];
                b[u][0] = *(const bf16x8*)&P[((size_t)(ntA*8 + kt)*64 + lane)*8];
                b[u][1] = *(const bf16x8*)&P[((size_t)((ntA+1)*8 + kt)*64 + lane)*8];
            }
            SCHED_FENCE();
            #pragma unroll
            for (int u = 0; u < 4; ++u) {
                acc[0][0] = MFMA(a[u][0], b[u][0], acc[0][0], 0,0,0);
                acc[0][1] = MFMA(a[u][1], b[u][0], acc[0][1], 0,0,0);
                acc[0][2] = MFMA(a[u][2], b[u][0], acc[0][2], 0,0,0);
                acc[1][0] = MFMA(a[u][0], b[u][1], acc[1][0], 0,0,0);
                acc[1][1] = MFMA(a[u][1], b[u][1], acc[1][1], 0,0,0);
                acc[1][2] = MFMA(a[u][2], b[u][1], acc[1][2], 0,0,0);
            }
        }
        #pragma unroll
        for (int i = 0; i < 2; ++i) {
            const int col = (ntA + i)*16 + lr;
            #pragma unroll
            for (int m = 0; m < 3; ++m)
                #pragma unroll
                for (int r = 0; r < 4; ++r) {
                    const int row = m*16 + quad*4 + r;
                    const float v = acc[i][m][r];
                    if (col < 256) {
                        if (row >= 2 && row < 34) qL[(row-2)*264 + col] = (__bf16)v;
                    } else if (row < 36) {
                        kvL[row*520 + (col - 256)] = (__bf16)v;
                    }
                }
        }
    }
}

// ---------------------------------------------------------------------------
// Attention (32 rows) from LDS qL/kvL -> cxL. (verified, unchanged)
// cxL MAY alias qL: each lane reads only the q chunk it later overwrites.
// ---------------------------------------------------------------------------
__device__ __forceinline__ void attn_lds(
    const __bf16* qL, const __bf16* kvL, __bf16* cxL, int s0, int tid)
{
    const int w = tid >> 6, lane = tid & 63, quad = lane >> 4, lr = lane & 15;
    const int r = 4*w + quad, s = s0 + r, ch0 = lr*16;

    float q[16];
    {
        bf16x8 q0 = *(const bf16x8*)&qL[r*264 + ch0];
        bf16x8 q1 = *(const bf16x8*)&qL[r*264 + ch0 + 8];
        #pragma unroll
        for (int i = 0; i < 8; ++i) { q[i] = (float)q0[i]; q[8+i] = (float)q1[i]; }
    }
    bf16x8 zv;
    #pragma unroll
    for (int i = 0; i < 8; ++i) zv[i] = (__bf16)0.f;

    const int offs[4] = {2, 1, -1, -2};
    float sc[4]; bf16x8 v0[4], v1[4];
    #pragma unroll
    for (int n = 0; n < 4; ++n) {
        const int s2 = s + offs[n];
        const bool ok = ((unsigned)s2 < 128u);
        const int lrow = r + offs[n] + 2;
        float p = 0.f;
        if (ok) {
            bf16x8 k0 = *(const bf16x8*)&kvL[lrow*520 + ch0];
            bf16x8 k1 = *(const bf16x8*)&kvL[lrow*520 + ch0 + 8];
            v0[n] = *(const bf16x8*)&kvL[lrow*520 + 256 + ch0];
            v1[n] = *(const bf16x8*)&kvL[lrow*520 + 256 + ch0 + 8];
            #pragma unroll
            for (int i = 0; i < 8; ++i) p += q[i]*(float)k0[i] + q[8+i]*(float)k1[i];
        } else { v0[n] = zv; v1[n] = zv; }
        p += __shfl_xor(p, 1);
        sc[n] = ok ? p * 0.17677669529663687f : 0.f;
    }
    const float mx = fmaxf(fmaxf(sc[0], sc[1]), fmaxf(sc[2], sc[3]));
    float se = 0.f, aw[4];
    #pragma unroll
    for (int n = 0; n < 4; ++n) { aw[n] = __expf(sc[n] - mx); se += aw[n]; }
    const float inv = 1.f / se;
    float cx[16];
    #pragma unroll
    for (int i = 0; i < 16; ++i) cx[i] = 0.f;
    #pragma unroll
    for (int n = 0; n < 4; ++n)
        #pragma unroll
        for (int i = 0; i < 8; ++i) {
            cx[i]   += aw[n]*(float)v0[n][i];
            cx[8+i] += aw[n]*(float)v1[n][i];
        }
    bf16x8 o0, o1;
    #pragma unroll
    for (int i = 0; i < 8; ++i) { o0[i] = (__bf16)(cx[i]*inv); o1[i] = (__bf16)(cx[8+i]*inv); }
    *(bf16x8*)&cxL[r*264 + ch0]     = o0;
    *(bf16x8*)&cxL[r*264 + ch0 + 8] = o1;
}

// ---------------------------------------------------------------------------
// step_k: ONE dispatch per scan step k (k = 0..NSTEP).
//
// Round-12 (extend the R11 fence win, same mechanism):
//  1. qkv chunks 2-kt -> 4-kt: 12 -> 6 exposed latency windows per wave.
//  2. Staging loops unrolled into {load group, fence, ds_write group}:
//     one exposed latency instead of 2-3 serialized load->write pairs.
//  3. Dec staging T14-style: halo loads issued to registers BEFORE the code
//     GEMM, written to LDS after it -> staging latency hides under ~32 MFMAs.
// All loads/values/MFMA order identical -> bit-identical results.
// Base: R11 (1118us; R9 XCD qt-swizzle, 4-barrier dec, fenced gates/code).
// ---------------------------------------------------------------------------
#define SM_A264   0
#define SM_R      19008
#define SM_Q      56448
#define SM_MISC   73344
#define SM_TOTAL  73856

__global__ __launch_bounds__(512, 4) void step_k(
    int k, const float* __restrict__ input,
    __bf16* __restrict__ P, __bf16* __restrict__ Q,
    const __bf16* __restrict__ Pqkv_e, const __bf16* __restrict__ Pqkv_d,
    const __bf16* __restrict__ Pemb,   const __bf16* __restrict__ Pg_e,
    const __bf16* __restrict__ Pg_d,
    const float* __restrict__ encWg, const float* __restrict__ encbg,
    const float* __restrict__ decbg, const float* __restrict__ embb,
    const float* __restrict__ outW,
    float* __restrict__ ec, float* __restrict__ outbuf,
    __bf16* __restrict__ codeS)
{
    __shared__ __attribute__((aligned(16))) char SM[SM_TOTAL];

    const int tid  = threadIdx.x;
    const int w    = tid >> 6;
    const int lane = tid & 63;
    const int quad = lane >> 4, lr = lane & 15;
    const int mt = w >> 2, ct = w & 3;

    // ---- R9 XCD-locality swizzle (verified best) ----
    const int p    = (int)blockIdx.x;
    const int qt   = (p >> 1) & 3;
    const int bh   = p & 1;
    const int j    = p >> 3;            // 0..63
    const bool isEnc = (j >= 32);
    const int b    = (bh << 3) | ((j >> 2) & 7);
    const int rg   = j & 3;

    const int gbatch = b*128, s0 = rg*32, grow0 = gbatch + s0;
    const int ch = qt*64 + ct*16 + lr;

    __bf16* aL  = (__bf16*)(SM + SM_A264);   // hL / dhL
    __bf16* kvL = (__bf16*)(SM + SM_R);
    __bf16* qL  = (__bf16*)(SM + SM_Q);
    __bf16* cxL = qL;                        // alias (safe, see attn_lds)

    if (isEnc) {
        // ===================== ENC body (step te = k) =====================
        if (k >= NSTEP) return;
        float* xL = (float*)(SM + SM_MISC);

        // hoisted scalar loads: latency overlaps staging + qkv + attn
        float wx0[4], wx1[4], wx2[4], bgv[4], ecv[4];
        #pragma unroll
        for (int g = 0; g < 4; ++g) {
            const int cc = g*256 + ch;
            wx0[g] = encWg[cc]; wx1[g] = encWg[1024 + cc]; wx2[g] = encWg[2048 + cc];
            bgv[g] = encbg[cc];
        }
        #pragma unroll
        for (int r = 0; r < 4; ++r)   // safe early read: only this thread writes it
            ecv[r] = ec[(size_t)(grow0 + mt*16 + quad*4 + r)*256 + ch];

        // stage eh_{k-1} halo rows: grouped loads, fence, grouped LDS writes
        {
            const __bf16* base = P + (size_t)gbatch*512;
            const int v0 = tid, v1 = tid + 512, v2 = tid + 1024;
            bf16x8 sv0 = ld_halo(base, s0, v0);
            bf16x8 sv1 = ld_halo(base, s0, v1);
            bf16x8 sv2;
            if (tid < 128) sv2 = ld_halo(base, s0, v2);
            float xv = 0.f;
            if (tid < 96) xv = input[((size_t)(b*Tz + k)*Sz + s0)*3 + tid];
            SCHED_FENCE();
            *(bf16x8*)&aL[(v0 >> 5)*264 + (v0 & 31)*8] = sv0;
            *(bf16x8*)&aL[(v1 >> 5)*264 + (v1 & 31)*8] = sv1;
            if (tid < 128) *(bf16x8*)&aL[(v2 >> 5)*264 + (v2 & 31)*8] = sv2;
            if (tid < 96) xL[tid] = xv;
        }
        __syncthreads();

        qkv_lds(aL, Pqkv_e, qL, kvL, tid);
        __syncthreads();
        attn_lds(qL, kvL, cxL, s0, tid);
        __syncthreads();

        // gates (K=512: aL own rows | cxL) + LSTM — 4-kt chunks, fenced
        f32x4 acc[4];
        #pragma unroll
        for (int g = 0; g < 4; ++g) acc[g] = f32x4{0.f,0.f,0.f,0.f};
        #pragma unroll
        for (int kc = 0; kc < 16; kc += 4) {
            bf16x8 a4[4], b4[4][4];
            #pragma unroll
            for (int uu = 0; uu < 4; ++uu) {
                const int kt = kc + uu;
                const __bf16* As = (kt < 8)
                    ? &aL [(2 + mt*16 + lr)*264 + kt*32 + quad*8]
                    : &cxL[(mt*16 + lr)*264 + (kt-8)*32 + quad*8];
                a4[uu] = *(const bf16x8*)As;
                #pragma unroll
                for (int g = 0; g < 4; ++g) {
                    const int nt = qt*16 + ct*4 + g;
                    b4[uu][g] = *(const bf16x8*)&Pg_e[((size_t)(nt*16 + kt)*64 + lane)*8];
                }
            }
            SCHED_FENCE();
            #pragma unroll
            for (int uu = 0; uu < 4; ++uu)
                #pragma unroll
                for (int g = 0; g < 4; ++g)
                    acc[g] = MFMA(a4[uu], b4[uu][g], acc[g], 0,0,0);
        }
        #pragma unroll
        for (int r = 0; r < 4; ++r) {
            const int row = mt*16 + quad*4 + r;
            const float x0 = xL[row*3], x1 = xL[row*3+1], x2 = xL[row*3+2];
            const float zi = acc[0][r] + x0*wx0[0] + x1*wx1[0] + x2*wx2[0] + bgv[0];
            const float zf = acc[1][r] + x0*wx0[1] + x1*wx1[1] + x2*wx2[1] + bgv[1];
            const float zg = acc[2][r] + x0*wx0[2] + x1*wx1[2] + x2*wx2[2] + bgv[2];
            const float zo = acc[3][r] + x0*wx0[3] + x1*wx1[3] + x2*wx2[3] + bgv[3];
            const size_t ei = (size_t)(grow0 + row)*256 + ch;
            const float cn = sigf(zf)*ecv[r] + sigf(zi)*tanhf(zg);
            ec[ei] = cn;
            Q[(size_t)(grow0 + row)*512 + ch] = (__bf16)(sigf(zo)*tanhf(cn));
        }
    } else {
        // ===================== DEC body (step td = k-1) =====================
        if (k < 1) return;
        const int td = k - 1;
        __bf16* dhL = aL;
        float* outredL = (float*)(SM + SM_MISC);
        __bf16* codeB = codeS + (size_t)((b*4 + rg)*4 + qt)*8192;  // 32x256

        // hoisted scalar loads
        float bgv[4];
        #pragma unroll
        for (int g = 0; g < 4; ++g) bgv[g] = decbg[g*256 + ch];
        const float ow  = outW[ch];
        const float bb0 = embb[(2*w + 0)*16 + lr];
        const float bb1 = embb[(2*w + 1)*16 + lr];

        // T14 issue-early: stage dh_{td-1} halo loads into REGISTERS now;
        // their latency hides under the entire code GEMM below.
        const __bf16* baseQ = Q + (size_t)gbatch*512 + 256;
        const int v0 = tid, v1 = tid + 512, v2 = tid + 1024;
        bf16x8 sv0 = ld_halo(baseQ, s0, v0);
        bf16x8 sv1 = ld_halo(baseQ, s0, v1);
        bf16x8 sv2;
        if (tid < 128) sv2 = ld_halo(baseQ, s0, v2);
        SCHED_FENCE();

        // code = sig(eh_{td} @ embW + embb) -> codeB (global scratch)
        // A direct from global P rows (no LDS).
        {
            const __bf16* Ae0 = P + (size_t)(grow0 + lr)*512;
            const __bf16* Ae1 = P + (size_t)(grow0 + 16 + lr)*512;
            f32x4 cacc[2][2];
            #pragma unroll
            for (int m = 0; m < 2; ++m)
                #pragma unroll
                for (int ii = 0; ii < 2; ++ii) cacc[m][ii] = f32x4{0.f,0.f,0.f,0.f};
            #pragma unroll
            for (int kc = 0; kc < 8; kc += 4) {
                bf16x8 a0s[4], a1s[4], bs[4][2];
                #pragma unroll
                for (int uu = 0; uu < 4; ++uu) {
                    const int kt = kc + uu;
                    a0s[uu] = *(const bf16x8*)&Ae0[kt*32 + quad*8];
                    a1s[uu] = *(const bf16x8*)&Ae1[kt*32 + quad*8];
                    #pragma unroll
                    for (int ii = 0; ii < 2; ++ii)
                        bs[uu][ii] = *(const bf16x8*)&Pemb[((size_t)((2*w + ii)*8 + kt)*64 + lane)*8];
                }
                SCHED_FENCE();
                #pragma unroll
                for (int uu = 0; uu < 4; ++uu)
                    #pragma unroll
                    for (int ii = 0; ii < 2; ++ii) {
                        cacc[0][ii] = MFMA(a0s[uu], bs[uu][ii], cacc[0][ii], 0,0,0);
                        cacc[1][ii] = MFMA(a1s[uu], bs[uu][ii], cacc[1][ii], 0,0,0);
                    }
            }
            #pragma unroll
            for (int ii = 0; ii < 2; ++ii) {
                const int col = (2*w + ii)*16 + lr;
                const float bb = (ii == 0) ? bb0 : bb1;
                #pragma unroll
                for (int m = 0; m < 2; ++m)
                    #pragma unroll
                    for (int r = 0; r < 4; ++r)
                        codeB[(size_t)(m*16 + quad*4 + r)*256 + col]
                            = (__bf16)sigf(cacc[m][ii][r] + bb);
            }
        }

        // write-late: staged halo rows land in LDS just before the barrier
        *(bf16x8*)&dhL[(v0 >> 5)*264 + (v0 & 31)*8] = sv0;
        *(bf16x8*)&dhL[(v1 >> 5)*264 + (v1 & 31)*8] = sv1;
        if (tid < 128) *(bf16x8*)&dhL[(v2 >> 5)*264 + (v2 & 31)*8] = sv2;
        __syncthreads();   // B1: dhL staged (codeB writes drained by vmcnt(0))

        // dec qkv from dh_{td-1} halo (LDS-staged, verified path)
        qkv_lds(dhL, Pqkv_d, qL, kvL, tid);
        __syncthreads();   // B2
        attn_lds(qL, kvL, cxL, s0, tid);
        __syncthreads();   // B3

        // gates kt 0..23 ascending (codeB | dhL own rows | cxL) — fenced chunks
        const __bf16* codeRow = codeB + (size_t)(mt*16 + lr)*256;
        f32x4 acc[4];
        #pragma unroll
        for (int g = 0; g < 4; ++g) acc[g] = f32x4{0.f,0.f,0.f,0.f};
        #pragma unroll
        for (int kc = 0; kc < 24; kc += 4) {
            bf16x8 a4[4], b4[4][4];
            #pragma unroll
            for (int uu = 0; uu < 4; ++uu) {
                const int kt = kc + uu;
                a4[uu] = (kt < 8)
                    ? *(const bf16x8*)&codeRow[kt*32 + quad*8]
                    : (kt < 16)
                    ? *(const bf16x8*)&dhL[(2 + mt*16 + lr)*264 + (kt-8)*32 + quad*8]
                    : *(const bf16x8*)&cxL[(mt*16 + lr)*264 + (kt-16)*32 + quad*8];
                #pragma unroll
                for (int g = 0; g < 4; ++g) {
                    const int nt = qt*16 + ct*4 + g;
                    b4[uu][g] = *(const bf16x8*)&Pg_d[((size_t)(nt*24 + kt)*64 + lane)*8];
                }
            }
            SCHED_FENCE();
            #pragma unroll
            for (int uu = 0; uu < 4; ++uu)
                #pragma unroll
                for (int g = 0; g < 4; ++g)
                    acc[g] = MFMA(a4[uu], b4[uu][g], acc[g], 0,0,0);
        }
        #pragma unroll
        for (int r = 0; r < 4; ++r) {
            const int row = mt*16 + quad*4 + r;
            const float zi = acc[0][r] + bgv[0];
            const float zf = acc[1][r] + bgv[1];
            const float zg = acc[2][r] + bgv[2];
            const float zo = acc[3][r] + bgv[3];
            const float c_old = (float)dhL[(2 + row)*264 + ch];
            const float cn = sigf(zf)*c_old + sigf(zi)*tanhf(zg);
            const float h  = sigf(zo)*tanhf(cn);
            P[(size_t)(grow0 + row)*512 + 256 + ch] = (__bf16)h;
            float pv = h * ow;
            pv += __shfl_xor(pv, 1); pv += __shfl_xor(pv, 2);
            pv += __shfl_xor(pv, 4); pv += __shfl_xor(pv, 8);
            if (lr == 0) outredL[row*4 + ct] = pv;
        }
        __syncthreads();   // B4
        if (tid < 32) {
            const float s4 = outredL[tid*4] + outredL[tid*4+1]
                           + outredL[tid*4+2] + outredL[tid*4+3];
            atomicAdd(&outbuf[(size_t)td*Mz + grow0 + tid], s4);
        }
    }
}

// ---------------------------------------------------------------------------
// Final assembly (unchanged, verified)
// ---------------------------------------------------------------------------
__global__ __launch_bounds__(256) void assemble_k(
    const float* __restrict__ outbuf, const float* __restrict__ input,
    const float* __restrict__ outb, float* __restrict__ out)
{
    const int idx = blockIdx.x*256 + threadIdx.x;
    const int NT = NSTEP - TPz;                 // 27
    if (idx >= Bz*NT*Sz) return;
    const int s  = idx & 127;
    const int bi = idx >> 7;
    const int i  = bi % NT;
    const int b  = bi / NT;
    const int t  = i + TPz;
    const float ob = outb[0];
    const float o  = outbuf[t*Mz + (b<<7) + s] + ob;
    const float In = (s == 0)
        ? input[((size_t)(b*Tz + t + 1)*Sz)*3 + 1]
        : outbuf[t*Mz + (b<<7) + s - 1] + ob;
    const float num = input[((size_t)(b*Tz + t)*Sz + s)*3 + 2] + In - o;
    const size_t base = ((size_t)(b*NT + i)*Sz + s)*3;
    out[base+0] = o;
    out[base+1] = In;
    out[base+2] = num;
}

// ---------------------------------------------------------------------------
extern "C" void kernel_launch(void* const* d_in, const int* in_sizes, int n_in,
                              void* d_out, int out_size, void* d_ws, size_t ws_size,
                              hipStream_t stream)
{
    const float* input = (const float*)d_in[0];
    const float* encWq = (const float*)d_in[1];
    const float* encWk = (const float*)d_in[2];
    const float* encWv = (const float*)d_in[3];
    const float* encWg = (const float*)d_in[4];
    const float* encbg = (const float*)d_in[5];
    const float* decWq = (const float*)d_in[6];
    const float* decWk = (const float*)d_in[7];
    const float* decWv = (const float*)d_in[8];
    const float* decWg = (const float*)d_in[9];
    const float* decbg = (const float*)d_in[10];
    const float* embW  = (const float*)d_in[11];
    const float* embb  = (const float*)d_in[12];
    const float* outW  = (const float*)d_in[13];
    const float* outb  = (const float*)d_in[14];

    char* ws = (char*)d_ws;
    size_t off = 0;
    auto alloc = [&](size_t bytes) -> void* {
        void* p = ws + off;
        off += (bytes + 255) & ~(size_t)255;
        return p;
    };
    __bf16* Pqkv_e = (__bf16*)alloc((size_t)768*256*2);
    __bf16* Pqkv_d = (__bf16*)alloc((size_t)768*256*2);
    __bf16* Pemb   = (__bf16*)alloc((size_t)256*256*2);
    __bf16* Pg_e   = (__bf16*)alloc((size_t)1024*512*2);
    __bf16* Pg_d   = (__bf16*)alloc((size_t)1024*768*2);
    __bf16* Xa     = (__bf16*)alloc((size_t)Mz*512*2);   // [ehb|dh] ping
    __bf16* Xb     = (__bf16*)alloc((size_t)Mz*512*2);   // pong
    float*  ec     = (float*) alloc((size_t)Mz*256*4);
    float*  outbuf = (float*) alloc((size_t)NSTEP*Mz*4);
    __bf16* codeS  = (__bf16*)alloc((size_t)256*32*256*2);  // dec code scratch

    hipMemsetAsync(Xa, 0, (size_t)Mz*512*2, stream);
    hipMemsetAsync(ec, 0, (size_t)Mz*256*4, stream);
    hipMemsetAsync(outbuf, 0, (size_t)NSTEP*Mz*4, stream);

    prep3<<<6912, 256, 0, stream>>>(encWq, encWk, encWv, encWg,
                                    decWq, decWk, decWv, decWg, embW,
                                    Pqkv_e, Pqkv_d, Pemb, Pg_e, Pg_d);

    for (int k = 0; k <= NSTEP; ++k) {
        __bf16* P = (k & 1) ? Xb : Xa;
        __bf16* Q = (k & 1) ? Xa : Xb;
        step_k<<<512, 512, 0, stream>>>(k, input, P, Q,
                                        Pqkv_e, Pqkv_d, Pemb, Pg_e, Pg_d,
                                        encWg, encbg, decbg, embb, outW,
                                        ec, outbuf, codeS);
    }
    assemble_k<<<(Bz*(NSTEP-TPz)*Sz + 255)/256, 256, 0, stream>>>(
        outbuf, input, outb, (float*)d_out);
}

// Round 14
// 1095.054 us; speedup vs baseline: 1.3539x; 1.3539x over previous
//
#include <hip/hip_runtime.h>
#include <hip/hip_bf16.h>

// Problem constants
#define Bz 16
#define Tz 32
#define Sz 128
#define TPz 4
#define Mz (Bz*Sz)          // 2048 rows
#define NSTEP (Tz-1)        // 31

typedef __bf16 bf16x8 __attribute__((ext_vector_type(8)));
typedef float  f32x4  __attribute__((ext_vector_type(4)));

#define MFMA __builtin_amdgcn_mfma_f32_16x16x32_bf16
#define SCHED_FENCE() __builtin_amdgcn_sched_barrier(0)

__device__ __forceinline__ float sigf(float x) { return 1.f/(1.f + __expf(-x)); }

// ---------------------------------------------------------------------------
// prep3 (verified): pack weights (fp32) into bf16 MFMA B-fragment order
// ---------------------------------------------------------------------------
__global__ __launch_bounds__(256) void prep3(
    const float* __restrict__ encWq, const float* __restrict__ encWk,
    const float* __restrict__ encWv, const float* __restrict__ encWg,
    const float* __restrict__ decWq, const float* __restrict__ decWk,
    const float* __restrict__ decWv, const float* __restrict__ decWg,
    const float* __restrict__ embW,
    __bf16* __restrict__ Pqkv_e, __bf16* __restrict__ Pqkv_d,
    __bf16* __restrict__ Pemb,   __bf16* __restrict__ Pg_e,
    __bf16* __restrict__ Pg_d)
{
    int id = blockIdx.x * 256 + threadIdx.x;
    if (id < 768*256) {
        int f = id >> 9, e = id & 511, l = e >> 3, j = e & 7;
        int nt = f >> 3, kt = f & 7;
        int n = nt*16 + (l & 15), k = kt*32 + (l >> 4)*8 + j;
        float v = (n < 256) ? encWq[k*256 + n]
                : (n < 512) ? encWk[k*256 + (n-256)]
                            : encWv[k*256 + (n-512)];
        Pqkv_e[id] = (__bf16)v; return;
    }
    id -= 768*256;
    if (id < 768*256) {
        int f = id >> 9, e = id & 511, l = e >> 3, j = e & 7;
        int nt = f >> 3, kt = f & 7;
        int n = nt*16 + (l & 15), k = kt*32 + (l >> 4)*8 + j;
        float v = (n < 256) ? decWq[k*256 + n]
                : (n < 512) ? decWk[k*256 + (n-256)]
                            : decWv[k*256 + (n-512)];
        Pqkv_d[id] = (__bf16)v; return;
    }
    id -= 768*256;
    if (id < 256*256) {
        int f = id >> 9, e = id & 511, l = e >> 3, j = e & 7;
        int nt = f >> 3, kt = f & 7;
        int n = nt*16 + (l & 15), k = kt*32 + (l >> 4)*8 + j;
        Pemb[id] = (__bf16)embW[k*256 + n]; return;
    }
    id -= 256*256;
    if (id < 1024*512) {
        int f = id >> 9, e = id & 511, l = e >> 3, j = e & 7;
        int nt = f >> 4, kt = f & 15;
        int cht = nt >> 2, g = nt & 3;
        int ch = cht*16 + (l & 15), k = kt*32 + (l >> 4)*8 + j;
        Pg_e[id] = (__bf16)encWg[(size_t)(3 + k)*1024 + g*256 + ch]; return;
    }
    id -= 1024*512;
    if (id < 1024*768) {
        int f = id >> 9, e = id & 511, l = e >> 3, j = e & 7;
        int nt = f / 24, kt = f % 24;
        int cht = nt >> 2, g = nt & 3;
        int ch = cht*16 + (l & 15), k = kt*32 + (l >> 4)*8 + j;
        Pg_d[id] = (__bf16)decWg[(size_t)k*1024 + g*256 + ch]; return;
    }
}

// ---------------------------------------------------------------------------
// qkv GEMM from 36-row staged state (stride 264) -> qL (own 32 rows), kvL (36).
// (verified R11) 2-kt chunks; sched_barrier(0) between each chunk's loads
// and its MFMAs. MFMA accumulation order unchanged.
// ---------------------------------------------------------------------------
__device__ __forceinline__ void qkv_lds(
    const __bf16* src264, const __bf16* __restrict__ P,
    __bf16* qL, __bf16* kvL, int tid)
{
    const int w = tid >> 6, lane = tid & 63, quad = (lane >> 4), lr = lane & 15;
    #pragma unroll
    for (int ng = 0; ng < 3; ++ng) {
        const int ntA = w*6 + ng*2;
        f32x4 acc[2][3];
        #pragma unroll
        for (int i = 0; i < 2; ++i)
            #pragma unroll
            for (int m = 0; m < 3; ++m) acc[i][m] = f32x4{0.f,0.f,0.f,0.f};
        #pragma unroll
        for (int kc = 0; kc < 8; kc += 2) {
            bf16x8 a[2][3], b[2][2];
            #pragma unroll
            for (int u = 0; u < 2; ++u) {
                const int kt = kc + u;
                a[u][0] = *(const bf16x8*)&src264[(lr)*264      + kt*32 + quad*8];
                a[u][1] = *(const bf16x8*)&src264[(16 + lr)*264 + kt*32 + quad*8];
                a[u][2] = *(const bf16x8*)&src264[(32 + lr)*264 + kt*32 + quad*8];
                b[u][0] = *(const bf16x8*)&P[((size_t)(ntA*8 + kt)*64 + lane)*8];
                b[u][1] = *(const bf16x8*)&P[((size_t)((ntA+1)*8 + kt)*64 + lane)*8];
            }
            SCHED_FENCE();
            #pragma unroll
            for (int u = 0; u < 2; ++u) {
                acc[0][0] = MFMA(a[u][0], b[u][0], acc[0][0], 0,0,0);
                acc[0][1] = MFMA(a[u][1], b[u][0], acc[0][1], 0,0,0);
                acc[0][2] = MFMA(a[u][2], b[u][0], acc[0][2], 0,0,0);
                acc[1][0] = MFMA(a[u][0], b[u][1], acc[1][0], 0,0,0);
                acc[1][1] = MFMA(a[u][1], b[u][1], acc[1][1], 0,0,0);
                acc[1][2] = MFMA(a[u][2], b[u][1], acc[1][2], 0,0,0);
            }
        }
        #pragma unroll
        for (int i = 0; i < 2; ++i) {
            const int col = (ntA + i)*16 + lr;
            #pragma unroll
            for (int m = 0; m < 3; ++m)
                #pragma unroll
                for (int r = 0; r < 4; ++r) {
                    const int row = m*16 + quad*4 + r;
                    const float v = acc[i][m][r];
                    if (col < 256) {
                        if (row >= 2 && row < 34) qL[(row-2)*264 + col] = (__bf16)v;
                    } else if (row < 36) {
                        kvL[row*520 + (col - 256)] = (__bf16)v;
                    }
                }
        }
    }
}

// ---------------------------------------------------------------------------
// Attention (32 rows) from LDS qL/kvL -> cxL. (verified, unchanged)
// cxL MAY alias qL: each lane reads only the q chunk it later overwrites.
// ---------------------------------------------------------------------------
__device__ __forceinline__ void attn_lds(
    const __bf16* qL, const __bf16* kvL, __bf16* cxL, int s0, int tid)
{
    const int w = tid >> 6, lane = tid & 63, quad = lane >> 4, lr = lane & 15;
    const int r = 4*w + quad, s = s0 + r, ch0 = lr*16;

    float q[16];
    {
        bf16x8 q0 = *(const bf16x8*)&qL[r*264 + ch0];
        bf16x8 q1 = *(const bf16x8*)&qL[r*264 + ch0 + 8];
        #pragma unroll
        for (int i = 0; i < 8; ++i) { q[i] = (float)q0[i]; q[8+i] = (float)q1[i]; }
    }
    bf16x8 zv;
    #pragma unroll
    for (int i = 0; i < 8; ++i) zv[i] = (__bf16)0.f;

    const int offs[4] = {2, 1, -1, -2};
    float sc[4]; bf16x8 v0[4], v1[4];
    #pragma unroll
    for (int n = 0; n < 4; ++n) {
        const int s2 = s + offs[n];
        const bool ok = ((unsigned)s2 < 128u);
        const int lrow = r + offs[n] + 2;
        float p = 0.f;
        if (ok) {
            bf16x8 k0 = *(const bf16x8*)&kvL[lrow*520 + ch0];
            bf16x8 k1 = *(const bf16x8*)&kvL[lrow*520 + ch0 + 8];
            v0[n] = *(const bf16x8*)&kvL[lrow*520 + 256 + ch0];
            v1[n] = *(const bf16x8*)&kvL[lrow*520 + 256 + ch0 + 8];
            #pragma unroll
            for (int i = 0; i < 8; ++i) p += q[i]*(float)k0[i] + q[8+i]*(float)k1[i];
        } else { v0[n] = zv; v1[n] = zv; }
        p += __shfl_xor(p, 1);
        sc[n] = ok ? p * 0.17677669529663687f : 0.f;
    }
    const float mx = fmaxf(fmaxf(sc[0], sc[1]), fmaxf(sc[2], sc[3]));
    float se = 0.f, aw[4];
    #pragma unroll
    for (int n = 0; n < 4; ++n) { aw[n] = __expf(sc[n] - mx); se += aw[n]; }
    const float inv = 1.f / se;
    float cx[16];
    #pragma unroll
    for (int i = 0; i < 16; ++i) cx[i] = 0.f;
    #pragma unroll
    for (int n = 0; n < 4; ++n)
        #pragma unroll
        for (int i = 0; i < 8; ++i) {
            cx[i]   += aw[n]*(float)v0[n][i];
            cx[8+i] += aw[n]*(float)v1[n][i];
        }
    bf16x8 o0, o1;
    #pragma unroll
    for (int i = 0; i < 8; ++i) { o0[i] = (__bf16)(cx[i]*inv); o1[i] = (__bf16)(cx[8+i]*inv); }
    *(bf16x8*)&cxL[r*264 + ch0]     = o0;
    *(bf16x8*)&cxL[r*264 + ch0 + 8] = o1;
}

// ---------------------------------------------------------------------------
// step_k: ONE dispatch per scan step k (k = 0..NSTEP).
//
// Round-14: base = R11 (verified best, 1118.6us). NO waves_per_eu attribute
// (3 of 4 submissions carrying it died on "container failed twice"; every
// attribute-free submission ran — suspected toolchain interaction).
// Single variable vs R11: gates + code-GEMM fenced chunks narrowed 4-kt ->
// 2-kt. R11's 4-kt groups hold 20 live bf16x8 (80 VGPRs) against the fixed
// 64-VGPR allocation -> scratch spill (WRITE 16.4 vs R9 15.4 MB/step).
// 2-kt groups (10-12 frags = 40-48 VGPRs) fit, keeping the fence's deep-MLP
// benefit without the spill round-trips. MFMA order unchanged everywhere
// (kt ascending) -> bit-identical results.
// ---------------------------------------------------------------------------
#define SM_A264   0
#define SM_R      19008
#define SM_Q      56448
#define SM_MISC   73344
#define SM_TOTAL  73856

__global__ __launch_bounds__(512, 4) void step_k(
    int k, const float* __restrict__ input,
    __bf16* __restrict__ P, __bf16* __restrict__ Q,
    const __bf16* __restrict__ Pqkv_e, const __bf16* __restrict__ Pqkv_d,
    const __bf16* __restrict__ Pemb,   const __bf16* __restrict__ Pg_e,
    const __bf16* __restrict__ Pg_d,
    const float* __restrict__ encWg, const float* __restrict__ encbg,
    const float* __restrict__ decbg, const float* __restrict__ embb,
    const float* __restrict__ outW,
    float* __restrict__ ec, float* __restrict__ outbuf,
    __bf16* __restrict__ codeS)
{
    __shared__ __attribute__((aligned(16))) char SM[SM_TOTAL];

    const int tid  = threadIdx.x;
    const int w    = tid >> 6;
    const int lane = tid & 63;
    const int quad = lane >> 4, lr = lane & 15;
    const int mt = w >> 2, ct = w & 3;

    // ---- R9 XCD-locality swizzle (verified best) ----
    const int p    = (int)blockIdx.x;
    const int qt   = (p >> 1) & 3;
    const int bh   = p & 1;
    const int j    = p >> 3;            // 0..63
    const bool isEnc = (j >= 32);
    const int b    = (bh << 3) | ((j >> 2) & 7);
    const int rg   = j & 3;

    const int gbatch = b*128, s0 = rg*32, grow0 = gbatch + s0;
    const int ch = qt*64 + ct*16 + lr;

    __bf16* aL  = (__bf16*)(SM + SM_A264);   // hL / dhL
    __bf16* kvL = (__bf16*)(SM + SM_R);
    __bf16* qL  = (__bf16*)(SM + SM_Q);
    __bf16* cxL = qL;                        // alias (safe, see attn_lds)

    if (isEnc) {
        // ===================== ENC body (step te = k) =====================
        if (k >= NSTEP) return;
        float* xL = (float*)(SM + SM_MISC);

        // hoisted scalar loads: latency overlaps staging + qkv + attn
        float wx0[4], wx1[4], wx2[4], bgv[4], ecv[4];
        #pragma unroll
        for (int g = 0; g < 4; ++g) {
            const int cc = g*256 + ch;
            wx0[g] = encWg[cc]; wx1[g] = encWg[1024 + cc]; wx2[g] = encWg[2048 + cc];
            bgv[g] = encbg[cc];
        }
        #pragma unroll
        for (int r = 0; r < 4; ++r)   // safe early read: only this thread writes it
            ecv[r] = ec[(size_t)(grow0 + mt*16 + quad*4 + r)*256 + ch];

        // stage eh_{k-1} halo rows (s0-2 .. s0+33) from P.enc
        for (int v = tid; v < 36*32; v += 512) {
            const int row = v >> 5, seg = v & 31, s = s0 - 2 + row;
            bf16x8 val;
            if ((unsigned)s < 128u)
                val = *(const bf16x8*)&P[(size_t)(gbatch + s)*512 + seg*8];
            else {
                #pragma unroll
                for (int ii = 0; ii < 8; ++ii) val[ii] = (__bf16)0.f;
            }
            *(bf16x8*)&aL[row*264 + seg*8] = val;
        }
        if (tid < 96) xL[tid] = input[((size_t)(b*Tz + k)*Sz + s0)*3 + tid];
        __syncthreads();

        qkv_lds(aL, Pqkv_e, qL, kvL, tid);
        __syncthreads();
        attn_lds(qL, kvL, cxL, s0, tid);
        __syncthreads();

        // gates (K=512: aL own rows | cxL) + LSTM — 2-kt chunks, fenced
        f32x4 acc[4];
        #pragma unroll
        for (int g = 0; g < 4; ++g) acc[g] = f32x4{0.f,0.f,0.f,0.f};
        #pragma unroll
        for (int kc = 0; kc < 16; kc += 2) {
            bf16x8 a2[2], b2[2][4];
            #pragma unroll
            for (int uu = 0; uu < 2; ++uu) {
                const int kt = kc + uu;
                const __bf16* As = (kt < 8)
                    ? &aL [(2 + mt*16 + lr)*264 + kt*32 + quad*8]
                    : &cxL[(mt*16 + lr)*264 + (kt-8)*32 + quad*8];
                a2[uu] = *(const bf16x8*)As;
                #pragma unroll
                for (int g = 0; g < 4; ++g) {
                    const int nt = qt*16 + ct*4 + g;
                    b2[uu][g] = *(const bf16x8*)&Pg_e[((size_t)(nt*16 + kt)*64 + lane)*8];
                }
            }
            SCHED_FENCE();
            #pragma unroll
            for (int uu = 0; uu < 2; ++uu)
                #pragma unroll
                for (int g = 0; g < 4; ++g)
                    acc[g] = MFMA(a2[uu], b2[uu][g], acc[g], 0,0,0);
        }
        #pragma unroll
        for (int r = 0; r < 4; ++r) {
            const int row = mt*16 + quad*4 + r;
            const float x0 = xL[row*3], x1 = xL[row*3+1], x2 = xL[row*3+2];
            const float zi = acc[0][r] + x0*wx0[0] + x1*wx1[0] + x2*wx2[0] + bgv[0];
            const float zf = acc[1][r] + x0*wx0[1] + x1*wx1[1] + x2*wx2[1] + bgv[1];
            const float zg = acc[2][r] + x0*wx0[2] + x1*wx1[2] + x2*wx2[2] + bgv[2];
            const float zo = acc[3][r] + x0*wx0[3] + x1*wx1[3] + x2*wx2[3] + bgv[3];
            const size_t ei = (size_t)(grow0 + row)*256 + ch;
            const float cn = sigf(zf)*ecv[r] + sigf(zi)*tanhf(zg);
            ec[ei] = cn;
            Q[(size_t)(grow0 + row)*512 + ch] = (__bf16)(sigf(zo)*tanhf(cn));
        }
    } else {
        // ===================== DEC body (step td = k-1) =====================
        if (k < 1) return;
        const int td = k - 1;
        __bf16* dhL = aL;
        float* outredL = (float*)(SM + SM_MISC);
        __bf16* codeB = codeS + (size_t)((b*4 + rg)*4 + qt)*8192;  // 32x256

        // hoisted scalar loads
        float bgv[4];
        #pragma unroll
        for (int g = 0; g < 4; ++g) bgv[g] = decbg[g*256 + ch];
        const float ow  = outW[ch];
        const float bb0 = embb[(2*w + 0)*16 + lr];
        const float bb1 = embb[(2*w + 1)*16 + lr];

        // stage dh_{td-1} halo (Q.dh) -> dhL
        for (int v = tid; v < 36*32; v += 512) {
            const int row = v >> 5, seg = v & 31, s = s0 - 2 + row;
            bf16x8 val;
            if ((unsigned)s < 128u)
                val = *(const bf16x8*)&Q[(size_t)(gbatch + s)*512 + 256 + seg*8];
            else {
                #pragma unroll
                for (int ii = 0; ii < 8; ++ii) val[ii] = (__bf16)0.f;
            }
            *(bf16x8*)&dhL[row*264 + seg*8] = val;
        }

        // code = sig(eh_{td} @ embW + embb) -> codeB (global scratch)
        // A direct from global P rows (no LDS); overlaps stage latency.
        {
            const __bf16* Ae0 = P + (size_t)(grow0 + lr)*512;
            const __bf16* Ae1 = P + (size_t)(grow0 + 16 + lr)*512;
            f32x4 cacc[2][2];
            #pragma unroll
            for (int m = 0; m < 2; ++m)
                #pragma unroll
                for (int ii = 0; ii < 2; ++ii) cacc[m][ii] = f32x4{0.f,0.f,0.f,0.f};
            #pragma unroll
            for (int kc = 0; kc < 8; kc += 2) {
                bf16x8 a0s[2], a1s[2], bs[2][2];
                #pragma unroll
                for (int uu = 0; uu < 2; ++uu) {
                    const int kt = kc + uu;
                    a0s[uu] = *(const bf16x8*)&Ae0[kt*32 + quad*8];
                    a1s[uu] = *(const bf16x8*)&Ae1[kt*32 + quad*8];
                    #pragma unroll
                    for (int ii = 0; ii < 2; ++ii)
                        bs[uu][ii] = *(const bf16x8*)&Pemb[((size_t)((2*w + ii)*8 + kt)*64 + lane)*8];
                }
                SCHED_FENCE();
                #pragma unroll
                for (int uu = 0; uu < 2; ++uu)
                    #pragma unroll
                    for (int ii = 0; ii < 2; ++ii) {
                        cacc[0][ii] = MFMA(a0s[uu], bs[uu][ii], cacc[0][ii], 0,0,0);
                        cacc[1][ii] = MFMA(a1s[uu], bs[uu][ii], cacc[1][ii], 0,0,0);
                    }
            }
            #pragma unroll
            for (int ii = 0; ii < 2; ++ii) {
                const int col = (2*w + ii)*16 + lr;
                const float bb = (ii == 0) ? bb0 : bb1;
                #pragma unroll
                for (int m = 0; m < 2; ++m)
                    #pragma unroll
                    for (int r = 0; r < 4; ++r)
                        codeB[(size_t)(m*16 + quad*4 + r)*256 + col]
                            = (__bf16)sigf(cacc[m][ii][r] + bb);
            }
        }
        __syncthreads();   // B1: dhL staged (codeB writes drained by vmcnt(0))

        // dec qkv from dh_{td-1} halo (LDS-staged, verified path)
        qkv_lds(dhL, Pqkv_d, qL, kvL, tid);
        __syncthreads();   // B2
        attn_lds(qL, kvL, cxL, s0, tid);
        __syncthreads();   // B3

        // gates kt 0..23 ascending (codeB | dhL own rows | cxL) — 2-kt fenced
        const __bf16* codeRow = codeB + (size_t)(mt*16 + lr)*256;
        f32x4 acc[4];
        #pragma unroll
        for (int g = 0; g < 4; ++g) acc[g] = f32x4{0.f,0.f,0.f,0.f};
        #pragma unroll
        for (int kc = 0; kc < 24; kc += 2) {
            bf16x8 a2[2], b2[2][4];
            #pragma unroll
            for (int uu = 0; uu < 2; ++uu) {
                const int kt = kc + uu;
                a2[uu] = (kt < 8)
                    ? *(const bf16x8*)&codeRow[kt*32 + quad*8]
                    : (kt < 16)
                    ? *(const bf16x8*)&dhL[(2 + mt*16 + lr)*264 + (kt-8)*32 + quad*8]
                    : *(const bf16x8*)&cxL[(mt*16 + lr)*264 + (kt-16)*32 + quad*8];
                #pragma unroll
                for (int g = 0; g < 4; ++g) {
                    const int nt = qt*16 + ct*4 + g;
                    b2[uu][g] = *(const bf16x8*)&Pg_d[((size_t)(nt*24 + kt)*64 + lane)*8];
                }
            }
            SCHED_FENCE();
            #pragma unroll
            for (int uu = 0; uu < 2; ++uu)
                #pragma unroll
                for (int g = 0; g < 4; ++g)
                    acc[g] = MFMA(a2[uu], b2[uu][g], acc[g], 0,0,0);
        }
        #pragma unroll
        for (int r = 0; r < 4; ++r) {
            const int row = mt*16 + quad*4 + r;
            const float zi = acc[0][r] + bgv[0];
            const float zf = acc[1][r] + bgv[1];
            const float zg = acc[2][r] + bgv[2];
            const float zo = acc[3][r] + bgv[3];
            const float c_old = (float)dhL[(2 + row)*264 + ch];
            const float cn = sigf(zf)*c_old + sigf(zi)*tanhf(zg);
            const float h  = sigf(zo)*tanhf(cn);
            P[(size_t)(grow0 + row)*512 + 256 + ch] = (__bf16)h;
            float pv = h * ow;
            pv += __shfl_xor(pv, 1); pv += __shfl_xor(pv, 2);
            pv += __shfl_xor(pv, 4); pv += __shfl_xor(pv, 8);
            if (lr == 0) outredL[row*4 + ct] = pv;
        }
        __syncthreads();   // B4
        if (tid < 32) {
            const float s4 = outredL[tid*4] + outredL[tid*4+1]
                           + outredL[tid*4+2] + outredL[tid*4+3];
            atomicAdd(&outbuf[(size_t)td*Mz + grow0 + tid], s4);
        }
    }
}

// ---------------------------------------------------------------------------
// Final assembly (unchanged, verified)
// ---------------------------------------------------------------------------
__global__ __launch_bounds__(256) void assemble_k(
    const float* __restrict__ outbuf, const float* __restrict__ input,
    const float* __restrict__ outb, float* __restrict__ out)
{
    const int idx = blockIdx.x*256 + threadIdx.x;
    const int NT = NSTEP - TPz;                 // 27
    if (idx >= Bz*NT*Sz) return;
    const int s  = idx & 127;
    const int bi = idx >> 7;
    const int i  = bi % NT;
    const int b  = bi / NT;
    const int t  = i + TPz;
    const float ob = outb[0];
    const float o  = outbuf[t*Mz + (b<<7) + s] + ob;
    const float In = (s == 0)
        ? input[((size_t)(b*Tz + t + 1)*Sz)*3 + 1]
        : outbuf[t*Mz + (b<<7) + s - 1] + ob;
    const float num = input[((size_t)(b*Tz + t)*Sz + s)*3 + 2] + In - o;
    const size_t base = ((size_t)(b*NT + i)*Sz + s)*3;
    out[base+0] = o;
    out[base+1] = In;
    out[base+2] = num;
}

// ---------------------------------------------------------------------------
extern "C" void kernel_launch(void* const* d_in, const int* in_sizes, int n_in,
                              void* d_out, int out_size, void* d_ws, size_t ws_size,
                              hipStream_t stream)
{
    const float* input = (const float*)d_in[0];
    const float* encWq = (const float*)d_in[1];
    const float* encWk = (const float*)d_in[2];
    const float* encWv = (const float*)d_in[3];
    const float* encWg = (const float*)d_in[4];
    const float* encbg = (const float*)d_in[5];
    const float* decWq = (const float*)d_in[6];
    const float* decWk = (const float*)d_in[7];
    const float* decWv = (const float*)d_in[8];
    const float* decWg = (const float*)d_in[9];
    const float* decbg = (const float*)d_in[10];
    const float* embW  = (const float*)d_in[11];
    const float* embb  = (const float*)d_in[12];
    const float* outW  = (const float*)d_in[13];
    const float* outb  = (const float*)d_in[14];

    char* ws = (char*)d_ws;
    size_t off = 0;
    auto alloc = [&](size_t bytes) -> void* {
        void* p = ws + off;
        off += (bytes + 255) & ~(size_t)255;
        return p;
    };
    __bf16* Pqkv_e = (__bf16*)alloc((size_t)768*256*2);
    __bf16* Pqkv_d = (__bf16*)alloc((size_t)768*256*2);
    __bf16* Pemb   = (__bf16*)alloc((size_t)256*256*2);
    __bf16* Pg_e   = (__bf16*)alloc((size_t)1024*512*2);
    __bf16* Pg_d   = (__bf16*)alloc((size_t)1024*768*2);
    __bf16* Xa     = (__bf16*)alloc((size_t)Mz*512*2);   // [ehb|dh] ping
    __bf16* Xb     = (__bf16*)alloc((size_t)Mz*512*2);   // pong
    float*  ec     = (float*) alloc((size_t)Mz*256*4);
    float*  outbuf = (float*) alloc((size_t)NSTEP*Mz*4);
    __bf16* codeS  = (__bf16*)alloc((size_t)256*32*256*2);  // dec code scratch

    hipMemsetAsync(Xa, 0, (size_t)Mz*512*2, stream);
    hipMemsetAsync(ec, 0, (size_t)Mz*256*4, stream);
    hipMemsetAsync(outbuf, 0, (size_t)NSTEP*Mz*4, stream);

    prep3<<<6912, 256, 0, stream>>>(encWq, encWk, encWv, encWg,
                                    decWq, decWk, decWv, decWg, embW,
                                    Pqkv_e, Pqkv_d, Pemb, Pg_e, Pg_d);

    for (int k = 0; k <= NSTEP; ++k) {
        __bf16* P = (k & 1) ? Xb : Xa;
        __bf16* Q = (k & 1) ? Xa : Xb;
        step_k<<<512, 512, 0, stream>>>(k, input, P, Q,
                                        Pqkv_e, Pqkv_d, Pemb, Pg_e, Pg_d,
                                        encWg, encbg, decbg, embb, outW,
                                        ec, outbuf, codeS);
    }
    assemble_k<<<(Bz*(NSTEP-TPz)*Sz + 255)/256, 256, 0, stream>>>(
        outbuf, input, outb, (float*)d_out);
}